// Round 1
// baseline (2756.853 us; speedup 1.0000x reference)
//
#include <hip/hip_runtime.h>

#define NNODES 100000
#define NEDGES 1600000
#define DIM    128
#define NEG_SLOPE 0.01f
#define TILE_R 32   // rows per gemm tile (100000 % 32 == 0 -> 3125 tiles)

// ---------------- zero h_neighbor ----------------
__global__ __launch_bounds__(256) void zero_f32(float* __restrict__ p, int n4) {
    int i = blockIdx.x * blockDim.x + threadIdx.x;
    int stride = gridDim.x * blockDim.x;
    float4 z = make_float4(0.f, 0.f, 0.f, 0.f);
    for (; i < n4; i += stride) ((float4*)p)[i] = z;
}

// ---------------- scatter: h_neighbor[dst] += nfeat[src] * w ----------------
// 32 lanes per edge, float4 per lane (32*4 = 128 = DIM)
__global__ __launch_bounds__(256) void scatter_edges(
    const float* __restrict__ nfeat, const int* __restrict__ esrc,
    const int* __restrict__ edst, const float* __restrict__ ew,
    float* __restrict__ hn) {
    long long t = (long long)blockIdx.x * 256 + threadIdx.x;
    int e = (int)(t >> 5);
    if (e >= NEDGES) return;
    int lane = (int)(t & 31);
    int s = esrc[e];
    int d = edst[e];
    float w = ew[e];
    float4 v = ((const float4*)(nfeat + (size_t)s * DIM))[lane];
    float* o = hn + (size_t)d * DIM + lane * 4;
    unsafeAtomicAdd(o + 0, v.x * w);
    unsafeAtomicAdd(o + 1, v.y * w);
    unsafeAtomicAdd(o + 2, v.z * w);
    unsafeAtomicAdd(o + 3, v.w * w);
}

// ---------------- out = leaky_relu((nfeat .* hn) @ W^T) ----------------
// Dynamic LDS: W as swizzled float4 chunks (64KB) + x tile (TILE_R x 128 f32, 16KB)
// W chunk (j, d4) stored at j*32 + (d4 ^ ((j>>2)&7))  -> conflict-free b128 reads
__global__ __launch_bounds__(256) void bi_gemm(
    const float* __restrict__ nfeat, const float* __restrict__ hn,
    const float* __restrict__ W, float* __restrict__ out) {
    extern __shared__ float lds[];
    float4* W4  = (float4*)lds;             // 128*32 float4 = 64KB
    float*  xs  = lds + 128 * 128;          // TILE_R*128 floats = 16KB
    float4* xs4 = (float4*)xs;

    int tid = threadIdx.x;

    // stage W swizzled (once per block)
    const float4* Wg = (const float4*)W;
    for (int i = tid; i < 128 * 32; i += 256) {
        int j = i >> 5, d4 = i & 31;
        W4[(j << 5) | (d4 ^ ((j >> 2) & 7))] = Wg[i];
    }
    __syncthreads();

    int tx = tid & 31;        // -> 4 output cols j0 = tx*4
    int ty = tid >> 5;        // -> 4 output rows r0 = ty*4
    int j0 = tx << 2;
    int r0 = ty << 2;

    int ntiles = NNODES / TILE_R;
    for (int tile = blockIdx.x; tile < ntiles; tile += gridDim.x) {
        int rbase = tile * TILE_R;

        // stage x = nfeat .* hn for TILE_R rows
        for (int i = tid; i < TILE_R * 32; i += 256) {
            int r = i >> 5, d4 = i & 31;
            size_t gi = ((size_t)(rbase + r) * DIM) / 4 + d4;
            float4 a = ((const float4*)nfeat)[gi];
            float4 b = ((const float4*)hn)[gi];
            float4 x;
            x.x = a.x * b.x; x.y = a.y * b.y; x.z = a.z * b.z; x.w = a.w * b.w;
            xs4[i] = x;
        }
        __syncthreads();

        float acc[4][4];
        #pragma unroll
        for (int r = 0; r < 4; ++r)
            #pragma unroll
            for (int j = 0; j < 4; ++j) acc[r][j] = 0.f;

        #pragma unroll 4
        for (int d4 = 0; d4 < 32; ++d4) {
            float4 xv[4], wv[4];
            #pragma unroll
            for (int r = 0; r < 4; ++r)
                xv[r] = xs4[((r0 + r) << 5) | d4];
            #pragma unroll
            for (int j = 0; j < 4; ++j) {
                int jj = j0 + j;
                wv[j] = W4[(jj << 5) | (d4 ^ ((jj >> 2) & 7))];
            }
            #pragma unroll
            for (int r = 0; r < 4; ++r)
                #pragma unroll
                for (int j = 0; j < 4; ++j) {
                    acc[r][j] += xv[r].x * wv[j].x;
                    acc[r][j] += xv[r].y * wv[j].y;
                    acc[r][j] += xv[r].z * wv[j].z;
                    acc[r][j] += xv[r].w * wv[j].w;
                }
        }
        __syncthreads();

        // epilogue: leaky_relu + store (coalesced float4 per row)
        #pragma unroll
        for (int r = 0; r < 4; ++r) {
            float4 o;
            o.x = acc[r][0] >= 0.f ? acc[r][0] : NEG_SLOPE * acc[r][0];
            o.y = acc[r][1] >= 0.f ? acc[r][1] : NEG_SLOPE * acc[r][1];
            o.z = acc[r][2] >= 0.f ? acc[r][2] : NEG_SLOPE * acc[r][2];
            o.w = acc[r][3] >= 0.f ? acc[r][3] : NEG_SLOPE * acc[r][3];
            size_t row = (size_t)(rbase + r0 + r);
            ((float4*)out)[row * (DIM / 4) + tx] = o;
        }
    }
}

extern "C" void kernel_launch(void* const* d_in, const int* in_sizes, int n_in,
                              void* d_out, int out_size, void* d_ws, size_t ws_size,
                              hipStream_t stream) {
    const float* nfeat = (const float*)d_in[0];
    const int*   esrc  = (const int*)d_in[1];
    const int*   edst  = (const int*)d_in[2];
    const float* ew    = (const float*)d_in[3];
    const float* W     = (const float*)d_in[4];
    float* out = (float*)d_out;
    float* hn  = (float*)d_ws;   // NNODES*DIM f32 = 51.2 MB

    static bool attr_set = false;
    if (!attr_set) {
        hipFuncSetAttribute((const void*)bi_gemm,
                            hipFuncAttributeMaxDynamicSharedMemorySize, 81920);
        attr_set = true;
    }

    zero_f32<<<2048, 256, 0, stream>>>(hn, NNODES * DIM / 4);

    int sgrid = (NEDGES * 32 + 255) / 256;
    scatter_edges<<<sgrid, 256, 0, stream>>>(nfeat, esrc, edst, ew, hn);

    bi_gemm<<<512, 256, 81920, stream>>>(nfeat, hn, W, out);
}

// Round 2
// 393.912 us; speedup vs baseline: 6.9986x; 6.9986x over previous
//
#include <hip/hip_runtime.h>

#define NNODES 100000
#define NEDGES 1600000
#define DIM    128
#define NEG_SLOPE 0.01f
#define TILE_R 32   // rows per gemm tile (100000 % 32 == 0 -> 3125 tiles)
#define NB_SCAN ((NNODES + 1023) / 1024)   // 98 blocks of 1024 counts

static inline size_t align256(size_t x) { return (x + 255) & ~(size_t)255; }

// ---------------- zero (also used for counts) ----------------
__global__ __launch_bounds__(256) void zero_f32(float* __restrict__ p, int n4) {
    int i = blockIdx.x * blockDim.x + threadIdx.x;
    int stride = gridDim.x * blockDim.x;
    float4 z = make_float4(0.f, 0.f, 0.f, 0.f);
    for (; i < n4; i += stride) ((float4*)p)[i] = z;
}

// ---------------- histogram of edge destinations ----------------
__global__ __launch_bounds__(256) void hist_dst(const int* __restrict__ edst,
                                                int* __restrict__ counts) {
    int e = blockIdx.x * 256 + threadIdx.x;
    if (e < NEDGES) atomicAdd(&counts[edst[e]], 1);
}

// ---------------- scan step 1: per-1024-chunk exclusive scan ----------------
__global__ __launch_bounds__(256) void scan1(const int* __restrict__ counts,
                                             int* __restrict__ offsets,
                                             int* __restrict__ blocksum) {
    __shared__ int lds[256];
    int tid = threadIdx.x;
    int base = blockIdx.x * 1024 + tid * 4;
    int c0 = (base + 0 < NNODES) ? counts[base + 0] : 0;
    int c1 = (base + 1 < NNODES) ? counts[base + 1] : 0;
    int c2 = (base + 2 < NNODES) ? counts[base + 2] : 0;
    int c3 = (base + 3 < NNODES) ? counts[base + 3] : 0;
    int t = c0 + c1 + c2 + c3;
    lds[tid] = t;
    __syncthreads();
    // Hillis-Steele inclusive scan over 256 per-thread sums
    for (int d = 1; d < 256; d <<= 1) {
        int v = lds[tid];
        int add = (tid >= d) ? lds[tid - d] : 0;
        __syncthreads();
        lds[tid] = v + add;
        __syncthreads();
    }
    int incl = lds[tid];
    int excl = incl - t;
    if (base + 0 < NNODES) offsets[base + 0] = excl;
    if (base + 1 < NNODES) offsets[base + 1] = excl + c0;
    if (base + 2 < NNODES) offsets[base + 2] = excl + c0 + c1;
    if (base + 3 < NNODES) offsets[base + 3] = excl + c0 + c1 + c2;
    if (tid == 255) blocksum[blockIdx.x] = incl;
}

// ---------------- scan step 2: serial exclusive scan of 98 block sums ----------------
__global__ void scan2(int* __restrict__ blocksum, int nb) {
    if (blockIdx.x == 0 && threadIdx.x == 0) {
        int acc = 0;
        for (int i = 0; i < nb; ++i) { int t = blocksum[i]; blocksum[i] = acc; acc += t; }
    }
}

// ---------------- scan step 3: add block offsets, init cursor ----------------
__global__ __launch_bounds__(256) void scan3(int* __restrict__ offsets,
                                             const int* __restrict__ blocksum,
                                             int* __restrict__ cursor) {
    int add = blocksum[blockIdx.x];
    int base = blockIdx.x * 1024 + threadIdx.x * 4;
    #pragma unroll
    for (int i = 0; i < 4; ++i) {
        int idx = base + i;
        if (idx < NNODES) { int o = offsets[idx] + add; offsets[idx] = o; cursor[idx] = o; }
    }
}

// ---------------- bin fill: bucket (src, w) by dst ----------------
__global__ __launch_bounds__(256) void fill_bins(const int* __restrict__ esrc,
                                                 const int* __restrict__ edst,
                                                 const float* __restrict__ ew,
                                                 int* __restrict__ cursor,
                                                 int* __restrict__ bsrc,
                                                 float* __restrict__ bw) {
    int e = blockIdx.x * 256 + threadIdx.x;
    if (e >= NEDGES) return;
    int d = edst[e];
    int p = atomicAdd(&cursor[d], 1);
    bsrc[p] = esrc[e];
    bw[p]   = ew[e];
}

// ---------------- pull: hn[v] = sum_{e in bucket v} w_e * nfeat[src_e] ----------------
// 32 lanes per node, float4 per lane; register accumulation, no atomics
__global__ __launch_bounds__(256) void pull_nodes(const float* __restrict__ nfeat,
                                                  const int* __restrict__ offsets,
                                                  const int* __restrict__ counts,
                                                  const int* __restrict__ bsrc,
                                                  const float* __restrict__ bw,
                                                  float* __restrict__ hn) {
    int gid = blockIdx.x * 256 + threadIdx.x;
    int v = gid >> 5;
    int lane = gid & 31;
    if (v >= NNODES) return;
    int start = offsets[v];
    int end = start + counts[v];
    const float4* nf4 = (const float4*)nfeat;
    float4 a0 = make_float4(0.f, 0.f, 0.f, 0.f);
    float4 a1 = make_float4(0.f, 0.f, 0.f, 0.f);
    int k = start;
    for (; k + 2 <= end; k += 2) {
        int s0 = bsrc[k], s1 = bsrc[k + 1];
        float w0 = bw[k], w1 = bw[k + 1];
        float4 v0 = nf4[(size_t)s0 * 32 + lane];
        float4 v1 = nf4[(size_t)s1 * 32 + lane];
        a0.x += w0 * v0.x; a0.y += w0 * v0.y; a0.z += w0 * v0.z; a0.w += w0 * v0.w;
        a1.x += w1 * v1.x; a1.y += w1 * v1.y; a1.z += w1 * v1.z; a1.w += w1 * v1.w;
    }
    if (k < end) {
        int s = bsrc[k]; float w = bw[k];
        float4 v0 = nf4[(size_t)s * 32 + lane];
        a0.x += w * v0.x; a0.y += w * v0.y; a0.z += w * v0.z; a0.w += w * v0.w;
    }
    float4 acc;
    acc.x = a0.x + a1.x; acc.y = a0.y + a1.y; acc.z = a0.z + a1.z; acc.w = a0.w + a1.w;
    ((float4*)hn)[(size_t)v * 32 + lane] = acc;
}

// ---------------- fallback scatter (atomics) ----------------
__global__ __launch_bounds__(256) void scatter_edges(
    const float* __restrict__ nfeat, const int* __restrict__ esrc,
    const int* __restrict__ edst, const float* __restrict__ ew,
    float* __restrict__ hn) {
    long long t = (long long)blockIdx.x * 256 + threadIdx.x;
    int e = (int)(t >> 5);
    if (e >= NEDGES) return;
    int lane = (int)(t & 31);
    int s = esrc[e];
    int d = edst[e];
    float w = ew[e];
    float4 v = ((const float4*)(nfeat + (size_t)s * DIM))[lane];
    float* o = hn + (size_t)d * DIM + lane * 4;
    unsafeAtomicAdd(o + 0, v.x * w);
    unsafeAtomicAdd(o + 1, v.y * w);
    unsafeAtomicAdd(o + 2, v.z * w);
    unsafeAtomicAdd(o + 3, v.w * w);
}

// ---------------- out = leaky_relu((nfeat .* hn) @ W^T) ----------------
__global__ __launch_bounds__(256) void bi_gemm(
    const float* __restrict__ nfeat, const float* __restrict__ hn,
    const float* __restrict__ W, float* __restrict__ out) {
    extern __shared__ float lds[];
    float4* W4  = (float4*)lds;             // 128*32 float4 = 64KB
    float*  xs  = lds + 128 * 128;          // TILE_R*128 floats = 16KB
    float4* xs4 = (float4*)xs;

    int tid = threadIdx.x;

    const float4* Wg = (const float4*)W;
    for (int i = tid; i < 128 * 32; i += 256) {
        int j = i >> 5, d4 = i & 31;
        W4[(j << 5) | (d4 ^ ((j >> 2) & 7))] = Wg[i];
    }
    __syncthreads();

    int tx = tid & 31;
    int ty = tid >> 5;
    int j0 = tx << 2;
    int r0 = ty << 2;

    int ntiles = NNODES / TILE_R;
    for (int tile = blockIdx.x; tile < ntiles; tile += gridDim.x) {
        int rbase = tile * TILE_R;

        for (int i = tid; i < TILE_R * 32; i += 256) {
            int r = i >> 5, d4 = i & 31;
            size_t gi = ((size_t)(rbase + r) * DIM) / 4 + d4;
            float4 a = ((const float4*)nfeat)[gi];
            float4 b = ((const float4*)hn)[gi];
            float4 x;
            x.x = a.x * b.x; x.y = a.y * b.y; x.z = a.z * b.z; x.w = a.w * b.w;
            xs4[i] = x;
        }
        __syncthreads();

        float acc[4][4];
        #pragma unroll
        for (int r = 0; r < 4; ++r)
            #pragma unroll
            for (int j = 0; j < 4; ++j) acc[r][j] = 0.f;

        #pragma unroll 4
        for (int d4 = 0; d4 < 32; ++d4) {
            float4 xv[4], wv[4];
            #pragma unroll
            for (int r = 0; r < 4; ++r)
                xv[r] = xs4[((r0 + r) << 5) | d4];
            #pragma unroll
            for (int j = 0; j < 4; ++j) {
                int jj = j0 + j;
                wv[j] = W4[(jj << 5) | (d4 ^ ((jj >> 2) & 7))];
            }
            #pragma unroll
            for (int r = 0; r < 4; ++r)
                #pragma unroll
                for (int j = 0; j < 4; ++j) {
                    acc[r][j] += xv[r].x * wv[j].x;
                    acc[r][j] += xv[r].y * wv[j].y;
                    acc[r][j] += xv[r].z * wv[j].z;
                    acc[r][j] += xv[r].w * wv[j].w;
                }
        }
        __syncthreads();

        #pragma unroll
        for (int r = 0; r < 4; ++r) {
            float4 o;
            o.x = acc[r][0] >= 0.f ? acc[r][0] : NEG_SLOPE * acc[r][0];
            o.y = acc[r][1] >= 0.f ? acc[r][1] : NEG_SLOPE * acc[r][1];
            o.z = acc[r][2] >= 0.f ? acc[r][2] : NEG_SLOPE * acc[r][2];
            o.w = acc[r][3] >= 0.f ? acc[r][3] : NEG_SLOPE * acc[r][3];
            size_t row = (size_t)(rbase + r0 + r);
            ((float4*)out)[row * (DIM / 4) + tx] = o;
        }
    }
}

extern "C" void kernel_launch(void* const* d_in, const int* in_sizes, int n_in,
                              void* d_out, int out_size, void* d_ws, size_t ws_size,
                              hipStream_t stream) {
    const float* nfeat = (const float*)d_in[0];
    const int*   esrc  = (const int*)d_in[1];
    const int*   edst  = (const int*)d_in[2];
    const float* ew    = (const float*)d_in[3];
    const float* W     = (const float*)d_in[4];
    float* out = (float*)d_out;

    hipFuncSetAttribute((const void*)bi_gemm,
                        hipFuncAttributeMaxDynamicSharedMemorySize, 81920);

    // ---- workspace layout ----
    size_t off = 0;
    size_t hn_off = off;       off += align256((size_t)NNODES * DIM * 4);  // 51.2 MB
    size_t cnt_off = off;      off += align256((size_t)NNODES * 4);
    size_t ofs_off = off;      off += align256((size_t)NNODES * 4);
    size_t cur_off = off;      off += align256((size_t)NNODES * 4);
    size_t bsum_off = off;     off += align256((size_t)NB_SCAN * 4);
    size_t bsrc_off = off;     off += align256((size_t)NEDGES * 4);
    size_t bw_off = off;       off += align256((size_t)NEDGES * 4);
    size_t need = off;

    char* ws = (char*)d_ws;
    float* hn = (float*)(ws + hn_off);

    if (ws_size >= need) {
        int* counts = (int*)(ws + cnt_off);
        int* offsets = (int*)(ws + ofs_off);
        int* cursor = (int*)(ws + cur_off);
        int* blocksum = (int*)(ws + bsum_off);
        int* bsrc = (int*)(ws + bsrc_off);
        float* bw = (float*)(ws + bw_off);

        zero_f32<<<128, 256, 0, stream>>>((float*)counts, NNODES / 4);
        int egrid = (NEDGES + 255) / 256;
        hist_dst<<<egrid, 256, 0, stream>>>(edst, counts);
        scan1<<<NB_SCAN, 256, 0, stream>>>(counts, offsets, blocksum);
        scan2<<<1, 64, 0, stream>>>(blocksum, NB_SCAN);
        scan3<<<NB_SCAN, 256, 0, stream>>>(offsets, blocksum, cursor);
        fill_bins<<<egrid, 256, 0, stream>>>(esrc, edst, ew, cursor, bsrc, bw);
        int pgrid = (NNODES * 32 + 255) / 256;
        pull_nodes<<<pgrid, 256, 0, stream>>>(nfeat, offsets, counts, bsrc, bw, hn);
    } else {
        // fallback: atomic scatter
        zero_f32<<<2048, 256, 0, stream>>>(hn, NNODES * DIM / 4);
        int sgrid = (NEDGES * 32 + 255) / 256;
        scatter_edges<<<sgrid, 256, 0, stream>>>(nfeat, esrc, edst, ew, hn);
    }

    bi_gemm<<<512, 256, 81920, stream>>>(nfeat, hn, W, out);
}